// Round 1
// baseline (2655.212 us; speedup 1.0000x reference)
//
#include <hip/hip_runtime.h>
#include <math.h>

#define NPTS 262144
#define BB 8
#define HH 512
#define WW 512
#define EPSV 1e-5f

// ---------------- rulebook ----------------

__global__ __launch_bounds__(256) void k_scatter(const int* __restrict__ idx,
                                                 int* __restrict__ grid) {
  int i = blockIdx.x * 256 + threadIdx.x;
  int b = idx[i * 3 + 0], y = idx[i * 3 + 1], x = idx[i * 3 + 2];
  grid[(b * HH + y) * WW + x] = i;
}

__global__ __launch_bounds__(256) void k_rulebook(const int* __restrict__ idx,
                                                  const int* __restrict__ grid,
                                                  int* __restrict__ nbr) {
  int i = blockIdx.x * 256 + threadIdx.x;
  int b = idx[i * 3 + 0], y = idx[i * 3 + 1], x = idx[i * 3 + 2];
  int t = 0;
  #pragma unroll
  for (int dy = -1; dy <= 1; ++dy) {
    #pragma unroll
    for (int dx = -1; dx <= 1; ++dx) {
      int ny = y + dy, nx = x + dx;
      int v = -1;
      if (ny >= 0 && ny < HH && nx >= 0 && nx < WW)
        v = grid[(b * HH + ny) * WW + nx];
      nbr[i * 9 + t] = v;
      ++t;
    }
  }
}

// ---------------- batchnorm stats ----------------

template <int CI>
__global__ __launch_bounds__(256) void k_stats(const float* __restrict__ x,
                                               float* __restrict__ sum,
                                               float* __restrict__ ssum) {
  const int RL = 256 / CI;
  int c = threadIdx.x & (CI - 1);
  int rl = threadIdx.x / CI;
  long long base = (long long)blockIdx.x * 1024;
  float s = 0.f, ss = 0.f;
  for (int r = rl; r < 1024; r += RL) {
    float v = x[(base + r) * CI + c];
    s += v;
    ss += v * v;
  }
  atomicAdd(&sum[c], s);
  atomicAdd(&ssum[c], ss);
}

template <int CI>
__global__ void k_finalize(const float* __restrict__ sum, const float* __restrict__ ssum,
                           const float* __restrict__ gam, const float* __restrict__ bet,
                           float* __restrict__ sc, float* __restrict__ sh) {
  int c = threadIdx.x;
  if (c < CI) {
    float m = sum[c] * (1.f / NPTS);
    float v = ssum[c] * (1.f / NPTS) - m * m;
    float s = gam[c] * rsqrtf(v + EPSV);
    sc[c] = s;
    sh[c] = bet[c] - m * s;
  }
}

// ---------------- conv as tiled gather-GEMM ----------------
// block tile: 64 points x 128 out-channels; thread tile 4pt x 8co.
// g[c][pt] transposed in LDS (stride 68 keeps float4 reads 16B-aligned,
// conflict-free on reads). Weights streamed from global (L1/L2 resident).

template <int CI, int TAPS, bool ACT>
__global__ __launch_bounds__(256) void k_conv(const float* __restrict__ src,
                                              const float* __restrict__ scale,
                                              const float* __restrict__ shift,
                                              const int* __restrict__ nbr,
                                              const float* __restrict__ wgt,
                                              float* __restrict__ dst) {
  __shared__ float g[CI][68];
  __shared__ float s_sc[CI], s_sh[CI];
  const int tid = threadIdx.x;
  const int base = blockIdx.x * 64;
  const int co0 = (tid & 15) * 8;
  const int pt0 = (tid >> 4) * 4;

  if constexpr (ACT) {
    for (int c = tid; c < CI; c += 256) {
      s_sc[c] = scale[c];
      s_sh[c] = shift[c];
    }
  }

  float acc[4][8];
  #pragma unroll
  for (int p = 0; p < 4; ++p)
    #pragma unroll
    for (int q = 0; q < 8; ++q) acc[p][q] = 0.f;

  const int row = tid >> 2;   // 0..63 point within tile
  const int seg = tid & 3;    // quarter of the channel range
  const int CH = CI / 4;      // channels per staging thread

  for (int k = 0; k < TAPS; ++k) {
    __syncthreads();
    int nid;
    if constexpr (TAPS == 1) {
      nid = base + row;
    } else {
      nid = nbr[(base + row) * 9 + k];
    }
    if (nid >= 0) {
      const float* srow = src + (long long)nid * CI + seg * CH;
      #pragma unroll
      for (int j = 0; j < CH; j += 4) {
        float4 v = *(const float4*)(srow + j);
        int c = seg * CH + j;
        if constexpr (ACT) {
          g[c + 0][row] = fmaxf(v.x * s_sc[c + 0] + s_sh[c + 0], 0.f);
          g[c + 1][row] = fmaxf(v.y * s_sc[c + 1] + s_sh[c + 1], 0.f);
          g[c + 2][row] = fmaxf(v.z * s_sc[c + 2] + s_sh[c + 2], 0.f);
          g[c + 3][row] = fmaxf(v.w * s_sc[c + 3] + s_sh[c + 3], 0.f);
        } else {
          g[c + 0][row] = v.x;
          g[c + 1][row] = v.y;
          g[c + 2][row] = v.z;
          g[c + 3][row] = v.w;
        }
      }
    } else {
      #pragma unroll
      for (int j = 0; j < CH; ++j) g[seg * CH + j][row] = 0.f;
    }
    __syncthreads();

    const float* wk = wgt + (long long)k * CI * 128;
    #pragma unroll 4
    for (int c = 0; c < CI; ++c) {
      float4 a = *(const float4*)(&g[c][pt0]);
      const float* wr = wk + c * 128 + co0;
      float4 w0 = *(const float4*)(wr);
      float4 w1 = *(const float4*)(wr + 4);
      float av[4] = {a.x, a.y, a.z, a.w};
      float wv[8] = {w0.x, w0.y, w0.z, w0.w, w1.x, w1.y, w1.z, w1.w};
      #pragma unroll
      for (int p = 0; p < 4; ++p)
        #pragma unroll
        for (int q = 0; q < 8; ++q) acc[p][q] += av[p] * wv[q];
    }
  }

  #pragma unroll
  for (int p = 0; p < 4; ++p) {
    long long r = (long long)(base + pt0 + p) * 128 + co0;
    float4 o0 = make_float4(acc[p][0], acc[p][1], acc[p][2], acc[p][3]);
    float4 o1 = make_float4(acc[p][4], acc[p][5], acc[p][6], acc[p][7]);
    *(float4*)(dst + r) = o0;
    *(float4*)(dst + r + 4) = o1;
  }
}

// ---------------- pooling / SE / final ----------------

__global__ __launch_bounds__(256) void k_pool(const float* __restrict__ out2,
                                              float* __restrict__ pooled) {
  int c = threadIdx.x & 127;
  int rh = threadIdx.x >> 7;
  long long base = (long long)blockIdx.x * 2048;
  float s = 0.f;
  for (int r = rh; r < 2048; r += 2) s += out2[(base + r) * 128 + c];
  int b = (int)(base >> 15);
  atomicAdd(&pooled[b * 128 + c], s);
}

__global__ __launch_bounds__(256) void k_se(const float* __restrict__ pooled,
                                            const float* __restrict__ fc1w,
                                            const float* __restrict__ fc1b,
                                            const float* __restrict__ fc2w,
                                            const float* __restrict__ fc2b,
                                            float* __restrict__ se) {
  __shared__ float h[8][32];
  int tid = threadIdx.x;
  int b = tid >> 5, j = tid & 31;
  float s = fc1b[j];
  for (int c = 0; c < 128; ++c)
    s += pooled[b * 128 + c] * (1.f / 32768.f) * fc1w[j * 128 + c];
  h[b][j] = fmaxf(s, 0.f);
  __syncthreads();
  for (int t = tid; t < 1024; t += 256) {
    int bb = t >> 7, c = t & 127;
    float s2 = fc2b[c];
    #pragma unroll
    for (int jj = 0; jj < 32; ++jj) s2 += h[bb][jj] * fc2w[c * 32 + jj];
    se[t] = 1.f / (1.f + expf(-s2));
  }
}

__global__ __launch_bounds__(256) void k_final(float* __restrict__ out,
                                               const float* __restrict__ id,
                                               const float* __restrict__ se) {
  long long i = ((long long)blockIdx.x * 256 + threadIdx.x) * 4;
  int co = (int)(i & 127);
  long long rowi = i >> 7;
  int b = (int)(rowi >> 15);
  float4 o = *(const float4*)(out + i);
  float4 d = *(const float4*)(id + i);
  float4 s = *(const float4*)(se + b * 128 + co);
  o.x = o.x * s.x + d.x;
  o.y = o.y * s.y + d.y;
  o.z = o.z * s.z + d.z;
  o.w = o.w * s.w + d.w;
  *(float4*)(out + i) = o;
}

// ---------------- launch ----------------

extern "C" void kernel_launch(void* const* d_in, const int* in_sizes, int n_in,
                              void* d_out, int out_size, void* d_ws, size_t ws_size,
                              hipStream_t stream) {
  const float* feats = (const float*)d_in[0];
  const int* indices = (const int*)d_in[1];
  const float* bn1_g = (const float*)d_in[2];
  const float* bn1_b = (const float*)d_in[3];
  const float* w1    = (const float*)d_in[4];
  const float* bn2_g = (const float*)d_in[5];
  const float* bn2_b = (const float*)d_in[6];
  const float* w2    = (const float*)d_in[7];
  const float* fc1w  = (const float*)d_in[8];
  const float* fc1b  = (const float*)d_in[9];
  const float* fc2w  = (const float*)d_in[10];
  const float* fc2b  = (const float*)d_in[11];
  const float* wskip = (const float*)d_in[12];
  float* out = (float*)d_out;

  // workspace layout
  int* grid_i = (int*)d_ws;                       // 8*512*512 ints   (8 MB)
  int* nbr = grid_i + (BB * HH * WW);             // N*9 ints         (9.4 MB)
  float* stats = (float*)(nbr + NPTS * 9);        // 4096 floats
  float* sum1 = stats, *ss1 = stats + 64, *sc1 = stats + 128, *sh1 = stats + 192;
  float* sum2 = stats + 256, *ss2 = stats + 384, *sc2 = stats + 512, *sh2 = stats + 640;
  float* pooled = stats + 768;                    // 1024
  float* se = stats + 1792;                       // 1024
  float* out1 = stats + 4096;                     // N*128 floats (134 MB), reused as id

  hipMemsetAsync(grid_i, 0xFF, (size_t)BB * HH * WW * 4, stream);  // grid = -1
  hipMemsetAsync(stats, 0, 4096 * 4, stream);

  k_scatter<<<NPTS / 256, 256, 0, stream>>>(indices, grid_i);
  k_rulebook<<<NPTS / 256, 256, 0, stream>>>(indices, grid_i, nbr);

  k_stats<64><<<NPTS / 1024, 256, 0, stream>>>(feats, sum1, ss1);
  k_finalize<64><<<1, 64, 0, stream>>>(sum1, ss1, bn1_g, bn1_b, sc1, sh1);

  k_conv<64, 9, true><<<NPTS / 64, 256, 0, stream>>>(feats, sc1, sh1, nbr, w1, out1);

  k_stats<128><<<NPTS / 1024, 256, 0, stream>>>(out1, sum2, ss2);
  k_finalize<128><<<1, 128, 0, stream>>>(sum2, ss2, bn2_g, bn2_b, sc2, sh2);

  k_conv<128, 9, true><<<NPTS / 64, 256, 0, stream>>>(out1, sc2, sh2, nbr, w2, out);

  // skip GEMM: id = feats @ w_skip  (overwrites out1, which is dead now)
  k_conv<64, 1, false><<<NPTS / 64, 256, 0, stream>>>(feats, nullptr, nullptr, nullptr,
                                                      wskip, out1);

  k_pool<<<128, 256, 0, stream>>>(out, pooled);
  k_se<<<1, 256, 0, stream>>>(pooled, fc1w, fc1b, fc2w, fc2b, se);
  k_final<<<NPTS * 128 / 1024, 256, 0, stream>>>(out, out1, se);
}

// Round 3
// 1217.408 us; speedup vs baseline: 2.1810x; 2.1810x over previous
//
#include <hip/hip_runtime.h>
#include <math.h>

#define NPTS 262144
#define BB 8
#define HH 512
#define WW 512
#define EPSV 1e-5f

typedef short short8v __attribute__((ext_vector_type(8)));
typedef short short4v __attribute__((ext_vector_type(4)));
typedef float float4v __attribute__((ext_vector_type(4)));
typedef unsigned short ushort;
typedef ushort ushort8v __attribute__((ext_vector_type(8)));

static __device__ __forceinline__ ushort f2bf(float f) {
  union { float f; unsigned u; } v;
  v.f = f;
  unsigned r = v.u + 0x7fffu + ((v.u >> 16) & 1u);  // round-to-nearest-even
  return (ushort)(r >> 16);
}

static __device__ __forceinline__ float bf2f(ushort h) {
  union { unsigned u; float f; } v;
  v.u = ((unsigned)h) << 16;
  return v.f;
}

// ---------------- rulebook ----------------

__global__ __launch_bounds__(256) void k_scatter(const int* __restrict__ idx,
                                                 int* __restrict__ grid) {
  int i = blockIdx.x * 256 + threadIdx.x;
  int b = idx[i * 3 + 0], y = idx[i * 3 + 1], x = idx[i * 3 + 2];
  grid[(b * HH + y) * WW + x] = i;
}

__global__ __launch_bounds__(256) void k_rulebook(const int* __restrict__ idx,
                                                  const int* __restrict__ grid,
                                                  int* __restrict__ nbr) {
  int i = blockIdx.x * 256 + threadIdx.x;
  int b = idx[i * 3 + 0], y = idx[i * 3 + 1], x = idx[i * 3 + 2];
  int t = 0;
  #pragma unroll
  for (int dy = -1; dy <= 1; ++dy) {
    #pragma unroll
    for (int dx = -1; dx <= 1; ++dx) {
      int ny = y + dy, nx = x + dx;
      int v = -1;
      if (ny >= 0 && ny < HH && nx >= 0 && nx < WW)
        v = grid[(b * HH + ny) * WW + nx];
      nbr[i * 9 + t] = v;
      ++t;
    }
  }
}

// ---------------- batchnorm stats ----------------

template <int CI>
__global__ __launch_bounds__(256) void k_stats(const float* __restrict__ x,
                                               float* __restrict__ sum,
                                               float* __restrict__ ssum) {
  const int RL = 256 / CI;
  int c = threadIdx.x & (CI - 1);
  int rl = threadIdx.x / CI;
  long long base = (long long)blockIdx.x * 1024;
  float s = 0.f, ss = 0.f;
  for (int r = rl; r < 1024; r += RL) {
    float v = x[(base + r) * CI + c];
    s += v;
    ss += v * v;
  }
  atomicAdd(&sum[c], s);
  atomicAdd(&ssum[c], ss);
}

// bf16-input stats (CI=128)
__global__ __launch_bounds__(256) void k_stats_bf(const ushort* __restrict__ x,
                                                  float* __restrict__ sum,
                                                  float* __restrict__ ssum) {
  int c = threadIdx.x & 127;
  int rl = threadIdx.x >> 7;
  long long base = (long long)blockIdx.x * 1024;
  float s = 0.f, ss = 0.f;
  for (int r = rl; r < 1024; r += 2) {
    float v = bf2f(x[(base + r) * 128 + c]);
    s += v;
    ss += v * v;
  }
  atomicAdd(&sum[c], s);
  atomicAdd(&ssum[c], ss);
}

template <int CI>
__global__ void k_finalize(const float* __restrict__ sum, const float* __restrict__ ssum,
                           const float* __restrict__ gam, const float* __restrict__ bet,
                           float* __restrict__ sc, float* __restrict__ sh) {
  int c = threadIdx.x;
  if (c < CI) {
    float m = sum[c] * (1.f / NPTS);
    float v = ssum[c] * (1.f / NPTS) - m * m;
    float s = gam[c] * rsqrtf(v + EPSV);
    sc[c] = s;
    sh[c] = bet[c] - m * s;
  }
}

// ---------------- weight prep: fp32 [taps][ci][128] -> bf16 [taps][128][ci] ----

__global__ __launch_bounds__(256) void k_wprep(const float* __restrict__ w,
                                               ushort* __restrict__ wt,
                                               int taps, int ci) {
  int i = blockIdx.x * 256 + threadIdx.x;
  int total = taps * ci * 128;
  if (i < total) {
    int t = i / (ci * 128);
    int rem = i - t * ci * 128;
    int c = rem >> 7;
    int o = rem & 127;
    wt[((size_t)t * 128 + o) * ci + c] = f2bf(w[i]);
  }
}

// ---------------- MFMA gather-GEMM conv ----------------
// Block: 256 thr = 4 waves; tile 128 pts x 128 cout. Wave (wm,wn) owns
// 64x64 = 4x4 MFMA 16x16x32 tiles. A staged [pt][k] bf16 (pad +8: row
// stride = 4 banks -> 2-way aliasing, free per m136); B staged [co][ci]
// from pre-transposed bf16 weights so frags are contiguous ds_read_b128.
// SrcT: float (fp32 rows) or ushort (bf16 rows). DstT: float or ushort(bf16).

template <typename SrcT, typename DstT, int CI, int TAPS, bool ACT>
__global__ __launch_bounds__(256) void k_conv(const SrcT* __restrict__ src,
                                              const float* __restrict__ scale,
                                              const float* __restrict__ shift,
                                              const int* __restrict__ nbr,
                                              const ushort* __restrict__ wt,
                                              DstT* __restrict__ dst) {
  constexpr int SA = CI + 8;
  __shared__ ushort As[128 * SA];
  __shared__ ushort Bs[128 * SA];
  __shared__ float s_sc[CI], s_sh[CI];

  const int tid = threadIdx.x;
  const int base = blockIdx.x * 128;
  const int lane = tid & 63;
  const int wave = tid >> 6;
  const int wm = wave & 1, wn = wave >> 1;
  const int m_base = wm * 64, n_base = wn * 64;
  const int fm = lane & 15;       // frag row/col-within-16
  const int fq = lane >> 4;       // quad 0..3

  if constexpr (ACT) {
    for (int c = tid; c < CI; c += 256) {
      s_sc[c] = scale[c];
      s_sh[c] = shift[c];
    }
  }
  __syncthreads();

  float4v acc[4][4];
  #pragma unroll
  for (int i = 0; i < 4; ++i)
    #pragma unroll
    for (int j = 0; j < 4; ++j) acc[i][j] = (float4v){0.f, 0.f, 0.f, 0.f};

  const int srow_i = tid >> 1;     // 0..127 staging row
  const int shalf = tid & 1;
  const int c0 = shalf * (CI / 2);

  for (int k = 0; k < TAPS; ++k) {
    if (k) __syncthreads();

    // ---- stage A (gather + optional BN/ReLU + bf16 convert) ----
    int nid;
    if constexpr (TAPS == 1) {
      nid = base + srow_i;
    } else {
      nid = nbr[(base + srow_i) * 9 + k];
    }
    ushort* arow = &As[srow_i * SA + c0];
    if (nid >= 0) {
      const SrcT* gsrc = src + (size_t)nid * CI + c0;
      if constexpr (sizeof(SrcT) == 4) {
        #pragma unroll
        for (int j = 0; j < CI / 2; j += 4) {
          float4 v = *(const float4*)((const float*)gsrc + j);
          if constexpr (ACT) {
            int c = c0 + j;
            v.x = fmaxf(v.x * s_sc[c + 0] + s_sh[c + 0], 0.f);
            v.y = fmaxf(v.y * s_sc[c + 1] + s_sh[c + 1], 0.f);
            v.z = fmaxf(v.z * s_sc[c + 2] + s_sh[c + 2], 0.f);
            v.w = fmaxf(v.w * s_sc[c + 3] + s_sh[c + 3], 0.f);
          }
          short4v o = {(short)f2bf(v.x), (short)f2bf(v.y), (short)f2bf(v.z), (short)f2bf(v.w)};
          *(short4v*)(arow + j) = o;
        }
      } else {
        #pragma unroll
        for (int j = 0; j < CI / 2; j += 8) {
          ushort8v raw = *(const ushort8v*)((const ushort*)gsrc + j);
          short8v o;
          #pragma unroll
          for (int e = 0; e < 8; ++e) {
            float f = bf2f(raw[e]);
            if constexpr (ACT) {
              int c = c0 + j + e;
              f = fmaxf(f * s_sc[c] + s_sh[c], 0.f);
            }
            o[e] = (short)f2bf(f);
          }
          *(short8v*)(arow + j) = o;
        }
      }
    } else {
      #pragma unroll
      for (int j = 0; j < CI / 2; j += 4)
        *(short4v*)(arow + j) = (short4v){0, 0, 0, 0};
    }

    // ---- stage B (copy transposed bf16 weights) ----
    {
      const ushort* wrow = wt + ((size_t)k * 128 + srow_i) * CI + c0;
      ushort* brow = &Bs[srow_i * SA + c0];
      #pragma unroll
      for (int j = 0; j < CI / 2; j += 8)
        *(uint4*)(brow + j) = *(const uint4*)(wrow + j);
    }
    __syncthreads();

    // ---- MFMA over this tap's K = CI ----
    #pragma unroll
    for (int kc = 0; kc < CI / 32; ++kc) {
      short8v af[4], bf[4];
      #pragma unroll
      for (int mi = 0; mi < 4; ++mi)
        af[mi] = *(const short8v*)(&As[(m_base + mi * 16 + fm) * SA + kc * 32 + fq * 8]);
      #pragma unroll
      for (int ni = 0; ni < 4; ++ni)
        bf[ni] = *(const short8v*)(&Bs[(n_base + ni * 16 + fm) * SA + kc * 32 + fq * 8]);
      #pragma unroll
      for (int mi = 0; mi < 4; ++mi)
        #pragma unroll
        for (int ni = 0; ni < 4; ++ni)
          acc[mi][ni] = __builtin_amdgcn_mfma_f32_16x16x32_bf16(af[mi], bf[ni], acc[mi][ni], 0, 0, 0);
    }
  }

  // ---- epilogue: C/D layout col=lane&15, row=quad*4+reg ----
  #pragma unroll
  for (int mi = 0; mi < 4; ++mi) {
    #pragma unroll
    for (int ni = 0; ni < 4; ++ni) {
      int pt = base + m_base + mi * 16 + fq * 4;
      int co = n_base + ni * 16 + fm;
      float4v c = acc[mi][ni];
      #pragma unroll
      for (int r = 0; r < 4; ++r) {
        if constexpr (sizeof(DstT) == 4)
          ((float*)dst)[(size_t)(pt + r) * 128 + co] = c[r];
        else
          ((ushort*)dst)[(size_t)(pt + r) * 128 + co] = f2bf(c[r]);
      }
    }
  }
}

// ---------------- pooling / SE / final ----------------

__global__ __launch_bounds__(256) void k_pool(const float* __restrict__ out2,
                                              float* __restrict__ pooled) {
  int c = threadIdx.x & 127;
  int rh = threadIdx.x >> 7;
  long long base = (long long)blockIdx.x * 2048;
  float s = 0.f;
  for (int r = rh; r < 2048; r += 2) s += out2[(base + r) * 128 + c];
  int b = (int)(base >> 15);
  atomicAdd(&pooled[b * 128 + c], s);
}

__global__ __launch_bounds__(256) void k_se(const float* __restrict__ pooled,
                                            const float* __restrict__ fc1w,
                                            const float* __restrict__ fc1b,
                                            const float* __restrict__ fc2w,
                                            const float* __restrict__ fc2b,
                                            float* __restrict__ se) {
  __shared__ float h[8][32];
  int tid = threadIdx.x;
  int b = tid >> 5, j = tid & 31;
  float s = fc1b[j];
  for (int c = 0; c < 128; ++c)
    s += pooled[b * 128 + c] * (1.f / 32768.f) * fc1w[j * 128 + c];
  h[b][j] = fmaxf(s, 0.f);
  __syncthreads();
  for (int t = tid; t < 1024; t += 256) {
    int bb = t >> 7, c = t & 127;
    float s2 = fc2b[c];
    #pragma unroll
    for (int jj = 0; jj < 32; ++jj) s2 += h[bb][jj] * fc2w[c * 32 + jj];
    se[t] = 1.f / (1.f + expf(-s2));
  }
}

__global__ __launch_bounds__(256) void k_final(float* __restrict__ out,
                                               const ushort* __restrict__ id,
                                               const float* __restrict__ se) {
  long long i = ((long long)blockIdx.x * 256 + threadIdx.x) * 4;
  int co = (int)(i & 127);
  long long rowi = i >> 7;
  int b = (int)(rowi >> 15);
  float4 o = *(const float4*)(out + i);
  ushort dh[4];
  *(uint2*)dh = *(const uint2*)(id + i);
  float4 s = *(const float4*)(se + b * 128 + co);
  o.x = o.x * s.x + bf2f(dh[0]);
  o.y = o.y * s.y + bf2f(dh[1]);
  o.z = o.z * s.z + bf2f(dh[2]);
  o.w = o.w * s.w + bf2f(dh[3]);
  *(float4*)(out + i) = o;
}

// ---------------- launch ----------------

extern "C" void kernel_launch(void* const* d_in, const int* in_sizes, int n_in,
                              void* d_out, int out_size, void* d_ws, size_t ws_size,
                              hipStream_t stream) {
  const float* feats = (const float*)d_in[0];
  const int* indices = (const int*)d_in[1];
  const float* bn1_g = (const float*)d_in[2];
  const float* bn1_b = (const float*)d_in[3];
  const float* w1    = (const float*)d_in[4];
  const float* bn2_g = (const float*)d_in[5];
  const float* bn2_b = (const float*)d_in[6];
  const float* w2    = (const float*)d_in[7];
  const float* fc1w  = (const float*)d_in[8];
  const float* fc1b  = (const float*)d_in[9];
  const float* fc2w  = (const float*)d_in[10];
  const float* fc2b  = (const float*)d_in[11];
  const float* wskip = (const float*)d_in[12];
  float* out = (float*)d_out;

  // workspace layout (~77 MB total; grid overlaid with out1/id, which are
  // only written after the rulebook kernels have consumed grid)
  char* p = (char*)d_ws;
  int* nbr = (int*)p;       p += (size_t)NPTS * 9 * 4;        // 9.44 MB
  float* stats = (float*)p; p += 4096 * 4;                    // 16 KB
  ushort* wt1 = (ushort*)p; p += (size_t)9 * 128 * 64 * 2;    // 144 KB
  ushort* wt2 = (ushort*)p; p += (size_t)9 * 128 * 128 * 2;   // 288 KB
  ushort* wts = (ushort*)p; p += (size_t)128 * 64 * 2;        // 16 KB
  p = (char*)(((size_t)p + 255) & ~(size_t)255);
  int* grid_i = (int*)p;          // 8 MB, dead after k_rulebook
  ushort* out1 = (ushort*)p;      // N*128 bf16 (67 MB), later reused as id

  float* sum1 = stats, *ss1 = stats + 64, *sc1 = stats + 128, *sh1 = stats + 192;
  float* sum2 = stats + 256, *ss2 = stats + 384, *sc2 = stats + 512, *sh2 = stats + 640;
  float* pooled = stats + 768;
  float* se = stats + 1792;

  hipMemsetAsync(grid_i, 0xFF, (size_t)BB * HH * WW * 4, stream);  // grid = -1
  hipMemsetAsync(stats, 0, 4096 * 4, stream);

  k_scatter<<<NPTS / 256, 256, 0, stream>>>(indices, grid_i);
  k_rulebook<<<NPTS / 256, 256, 0, stream>>>(indices, grid_i, nbr);

  // bf16 transposed weights
  k_wprep<<<(9 * 64 * 128 + 255) / 256, 256, 0, stream>>>(w1, wt1, 9, 64);
  k_wprep<<<(9 * 128 * 128 + 255) / 256, 256, 0, stream>>>(w2, wt2, 9, 128);
  k_wprep<<<(64 * 128 + 255) / 256, 256, 0, stream>>>(wskip, wts, 1, 64);

  k_stats<64><<<NPTS / 1024, 256, 0, stream>>>(feats, sum1, ss1);
  k_finalize<64><<<1, 64, 0, stream>>>(sum1, ss1, bn1_g, bn1_b, sc1, sh1);

  // conv1: relu(bn1(feats)) gathered -> MFMA -> out1 bf16
  k_conv<float, ushort, 64, 9, true><<<NPTS / 128, 256, 0, stream>>>(
      feats, sc1, sh1, nbr, wt1, out1);

  k_stats_bf<<<NPTS / 1024, 256, 0, stream>>>(out1, sum2, ss2);
  k_finalize<128><<<1, 128, 0, stream>>>(sum2, ss2, bn2_g, bn2_b, sc2, sh2);

  // conv2: relu(bn2(out1)) gathered -> MFMA -> out fp32
  k_conv<ushort, float, 128, 9, true><<<NPTS / 128, 256, 0, stream>>>(
      out1, sc2, sh2, nbr, wt2, out);

  // skip GEMM (out1 dead after conv2): id = feats @ w_skip -> bf16 in out1's space
  k_conv<float, ushort, 64, 1, false><<<NPTS / 128, 256, 0, stream>>>(
      feats, nullptr, nullptr, nullptr, wts, out1);

  k_pool<<<128, 256, 0, stream>>>(out, pooled);
  k_se<<<1, 256, 0, stream>>>(pooled, fc1w, fc1b, fc2w, fc2b, se);
  k_final<<<NPTS * 128 / 1024, 256, 0, stream>>>(out, out1, se);
}